// Round 1
// baseline (7089.605 us; speedup 1.0000x reference)
//
#include <hip/hip_runtime.h>
#include <hip/hip_bf16.h>
#include <math.h>

#define NB 64
#define PP 7

// ---------------------------------------------------------------------------
// crop_avg: x [N,C,H,H] f32, patchs [N,7,4] int (y0,y1,x0,x1 at 56-scale).
// Scaled coords: v' = v*num/den (floor). Box sum / area; zero if patch all-0.
// One block per (n,c) plane; plane staged in LDS; wave w sums rows y0+w+4k,
// lanes cover columns (width <= 56 <= 64).
// ---------------------------------------------------------------------------
__global__ __launch_bounds__(256) void crop_avg_kernel(
    const float* __restrict__ x, const int* __restrict__ patchs,
    float* __restrict__ out, int C, int H, int num, int den,
    int ldo, int col0)
{
    int c = blockIdx.x, n = blockIdx.y;
    extern __shared__ float sm[];
    __shared__ float red[4];
    const float* plane = x + ((size_t)n * C + c) * H * H;
    int tid = threadIdx.x;
    int sz = H * H;
    for (int i = tid; i < sz; i += 256) sm[i] = plane[i];
    __syncthreads();
    int lane = tid & 63, wv = tid >> 6;
    for (int p = 0; p < PP; ++p) {
        int p0 = patchs[(n * PP + p) * 4 + 0];
        int p1 = patchs[(n * PP + p) * 4 + 1];
        int p2 = patchs[(n * PP + p) * 4 + 2];
        int p3 = patchs[(n * PP + p) * 4 + 3];
        int y0 = p0 * num / den, y1 = p1 * num / den;
        int x0 = p2 * num / den, x1 = p3 * num / den;
        float partial = 0.f;
        int xx = x0 + lane;
        if (xx <= x1) {
            for (int y = y0 + wv; y <= y1; y += 4)
                partial += sm[y * H + xx];
        }
        #pragma unroll
        for (int off = 32; off; off >>= 1)
            partial += __shfl_down(partial, off, 64);
        if (lane == 0) red[wv] = partial;
        __syncthreads();
        if (tid == 0) {
            float tot = red[0] + red[1] + red[2] + red[3];
            float area = (float)((y1 - y0 + 1) * (x1 - x0 + 1));
            float v = tot / area;
            if (p0 == 0 && p1 == 0 && p2 == 0 && p3 == 0) v = 0.f;
            out[(size_t)(n * PP + p) * ldo + col0 + c] = v;
        }
        __syncthreads();
    }
}

// ---------------------------------------------------------------------------
// Generic fp32 gemm: out[m,o] = sum_k X[m*ldx+k] * W[o*K+k]
//                    (+ bias[o]) (+ add[m*ldadd+o]) (relu optional)
// Tile 64x64x64, 256 threads, 4x4 per thread. M multiple of 64; O guarded.
// ---------------------------------------------------------------------------
__global__ __launch_bounds__(256) void gemm_kernel(
    const float* __restrict__ X, int ldx,
    const float* __restrict__ W,
    const float* __restrict__ bias,
    const float* __restrict__ add, int ldadd,
    float* __restrict__ out, int ldo,
    int M, int O, int K, int relu)
{
    __shared__ float Xs[64][65];
    __shared__ float Ws[64][65];
    int m0 = blockIdx.y * 64, o0 = blockIdx.x * 64;
    int tid = threadIdx.x;
    int to = tid & 15, tm = tid >> 4;
    float acc[4][4] = {};
    for (int k0 = 0; k0 < K; k0 += 64) {
        #pragma unroll
        for (int i = 0; i < 16; ++i) {
            int idx = i * 256 + tid;
            int r = idx >> 6, cl = idx & 63;
            Xs[r][cl] = X[(size_t)(m0 + r) * ldx + k0 + cl];
            int o = o0 + r;
            Ws[r][cl] = (o < O) ? W[(size_t)o * K + k0 + cl] : 0.f;
        }
        __syncthreads();
        #pragma unroll 8
        for (int kk = 0; kk < 64; ++kk) {
            float xr[4], wr[4];
            #pragma unroll
            for (int i = 0; i < 4; ++i) xr[i] = Xs[tm * 4 + i][kk];
            #pragma unroll
            for (int j = 0; j < 4; ++j) wr[j] = Ws[to * 4 + j][kk];
            #pragma unroll
            for (int i = 0; i < 4; ++i)
                #pragma unroll
                for (int j = 0; j < 4; ++j)
                    acc[i][j] += xr[i] * wr[j];
        }
        __syncthreads();
    }
    #pragma unroll
    for (int i = 0; i < 4; ++i) {
        int m = m0 + tm * 4 + i;
        #pragma unroll
        for (int j = 0; j < 4; ++j) {
            int o = o0 + to * 4 + j;
            if (o < O) {
                float v = acc[i][j];
                if (bias) v += bias[o];
                if (add) v += add[(size_t)m * ldadd + o];
                if (relu) v = fmaxf(v, 0.f);
                out[(size_t)m * ldo + o] = v;
            }
        }
    }
}

// ---------------------------------------------------------------------------
// LSTM cell (torch gate order i,f,g,o). gates [64,4H]; h,c [64,H].
// h also written to dest[m*ldd + j] (pre-offset for (t, col0)).
// ---------------------------------------------------------------------------
__global__ __launch_bounds__(256) void lstm_cell_kernel(
    const float* __restrict__ gates, float* __restrict__ h,
    float* __restrict__ c, float* __restrict__ dest,
    int Hd, int ldd)
{
    int idx = blockIdx.x * 256 + threadIdx.x;
    if (idx >= NB * Hd) return;
    int m = idx / Hd, j = idx - m * Hd;
    const float* g = gates + (size_t)m * 4 * Hd;
    float gi = g[j], gf = g[Hd + j], gg = g[2 * Hd + j], go = g[3 * Hd + j];
    float si = 1.f / (1.f + expf(-gi));
    float sf = 1.f / (1.f + expf(-gf));
    float so = 1.f / (1.f + expf(-go));
    float cn = sf * c[idx] + si * tanhf(gg);
    float hn = so * tanhf(cn);
    c[idx] = cn;
    h[idx] = hn;
    dest[(size_t)m * ldd + j] = hn;
}

// ---------------------------------------------------------------------------
// softmax over 7 attn logits + weighted pool of rnn3 -> feat [64,1792]
// ---------------------------------------------------------------------------
__global__ __launch_bounds__(256) void attn_pool_kernel(
    const float* __restrict__ attn, const float* __restrict__ rnn3,
    float* __restrict__ feat)
{
    int n = blockIdx.x;
    __shared__ float alpha[PP];
    if (threadIdx.x == 0) {
        float a[PP], mx = -1e30f;
        for (int p = 0; p < PP; ++p) { a[p] = attn[n * PP + p]; mx = fmaxf(mx, a[p]); }
        float s = 0.f;
        for (int p = 0; p < PP; ++p) { a[p] = expf(a[p] - mx); s += a[p]; }
        for (int p = 0; p < PP; ++p) alpha[p] = a[p] / s;
    }
    __syncthreads();
    for (int j = threadIdx.x; j < 1792; j += 256) {
        float s = 0.f;
        #pragma unroll
        for (int p = 0; p < PP; ++p)
            s += rnn3[((size_t)n * PP + p) * 1792 + j] * alpha[p];
        feat[(size_t)n * 1792 + j] = s;
    }
}

// ---------------------------------------------------------------------------

extern "C" void kernel_launch(void* const* d_in, const int* in_sizes, int n_in,
                              void* d_out, int out_size, void* d_ws, size_t ws_size,
                              hipStream_t stream) {
    const float* x1 = (const float*)d_in[0];
    const float* x2 = (const float*)d_in[1];
    const float* x3 = (const float*)d_in[2];
    const int* patchs = (const int*)d_in[3];
    const float* l1_wih = (const float*)d_in[4];
    const float* l1_whh = (const float*)d_in[5];
    const float* l1_b   = (const float*)d_in[6];
    const float* l2_wih = (const float*)d_in[7];
    const float* l2_whh = (const float*)d_in[8];
    const float* l2_b   = (const float*)d_in[9];
    const float* l3_wih = (const float*)d_in[10];
    const float* l3_whh = (const float*)d_in[11];
    const float* l3_b   = (const float*)d_in[12];
    const float* aw1 = (const float*)d_in[13];
    const float* ab1 = (const float*)d_in[14];
    const float* aw2 = (const float*)d_in[15];
    const float* ab2 = (const float*)d_in[16];
    const float* aw3 = (const float*)d_in[17];
    const float* ab3 = (const float*)d_in[18];
    const float* fw  = (const float*)d_in[19];
    const float* fb  = (const float*)d_in[20];
    float* out = (float*)d_out;

    // workspace layout (floats)
    float* ws = (float*)d_ws;
    size_t o_local1 = 0;                          // [448,256]
    size_t o_local2 = o_local1 + 448 * 256;       // [448,768]
    size_t o_local3 = o_local2 + 448 * 768;       // [448,1792]
    size_t o_xg     = o_local3 + 448 * 1792;      // [448,7168] (reused)
    size_t o_rnn3   = o_xg + (size_t)448 * 7168;  // [448,1792]
    size_t o_gates  = o_rnn3 + 448 * 1792;        // [64,7168]
    size_t o_h      = o_gates + 64 * 7168;        // [64,1792]
    size_t o_c      = o_h + 64 * 1792;            // [64,1792]
    size_t o_h1     = o_c + 64 * 1792;            // [64,3584]
    size_t o_h2     = o_h1 + 64 * 3584;           // [64,1792]
    size_t o_attn   = o_h2 + 64 * 1792;           // [64,7]
    size_t o_feat   = o_attn + 64 * 8;            // [64,1792]
    float* local1 = ws + o_local1;
    float* local2 = ws + o_local2;
    float* local3 = ws + o_local3;
    float* xg     = ws + o_xg;
    float* rnn3   = ws + o_rnn3;
    float* gates  = ws + o_gates;
    float* hbuf   = ws + o_h;
    float* cbuf   = ws + o_c;
    float* h1     = ws + o_h1;
    float* h2     = ws + o_h2;
    float* attnb  = ws + o_attn;
    float* feat   = ws + o_feat;

    // ---- crops ----
    crop_avg_kernel<<<dim3(256, NB), 256, 56 * 56 * 4, stream>>>(
        x1, patchs, local1, 256, 56, 55, 55, 256, 0);
    crop_avg_kernel<<<dim3(512, NB), 256, 28 * 28 * 4, stream>>>(
        x2, patchs, local2, 512, 28, 27, 55, 768, 0);
    crop_avg_kernel<<<dim3(1024, NB), 256, 14 * 14 * 4, stream>>>(
        x3, patchs, local3, 1024, 14, 13, 55, 1792, 0);

    // ---- LSTM runner ----
    struct LstmCfg {
        const float *Xbuf, *wih, *whh, *b;
        int D, H;
        float* dest_base; int destHT, col0;
    };
    LstmCfg cfgs[3] = {
        { local1, l1_wih, l1_whh, l1_b, 256, 256, local2, 768, 512 },
        { local2, l2_wih, l2_whh, l2_b, 768, 768, local3, 1792, 1024 },
        { local3, l3_wih, l3_whh, l3_b, 1792, 1792, rnn3, 1792, 0 },
    };
    for (int L = 0; L < 3; ++L) {
        LstmCfg& cf = cfgs[L];
        int H4 = 4 * cf.H;
        // xg = X @ wih^T + b : [448, 4H]
        gemm_kernel<<<dim3((H4 + 63) / 64, 7), 256, 0, stream>>>(
            cf.Xbuf, cf.D, cf.wih, cf.b, nullptr, 0, xg, H4, 448, H4, cf.D, 0);
        hipMemsetAsync(hbuf, 0, (size_t)NB * cf.H * 4, stream);
        hipMemsetAsync(cbuf, 0, (size_t)NB * cf.H * 4, stream);
        for (int t = 0; t < PP; ++t) {
            // gates = xg[:,t,:] + h @ whh^T
            gemm_kernel<<<dim3((H4 + 63) / 64, 1), 256, 0, stream>>>(
                hbuf, cf.H, cf.whh, nullptr, xg + (size_t)t * H4, PP * H4,
                gates, H4, NB, H4, cf.H, 0);
            float* dest = cf.dest_base + (size_t)t * cf.destHT + cf.col0;
            lstm_cell_kernel<<<(NB * cf.H + 255) / 256, 256, 0, stream>>>(
                gates, hbuf, cbuf, dest, cf.H, PP * cf.destHT);
        }
    }

    // ---- attention MLP ----
    gemm_kernel<<<dim3(3584 / 64, 1), 256, 0, stream>>>(
        rnn3, 12544, aw1, ab1, nullptr, 0, h1, 3584, 64, 3584, 12544, 1);
    gemm_kernel<<<dim3(1792 / 64, 1), 256, 0, stream>>>(
        h1, 3584, aw2, ab2, nullptr, 0, h2, 1792, 64, 1792, 3584, 1);
    gemm_kernel<<<dim3(1, 1), 256, 0, stream>>>(
        h2, 1792, aw3, ab3, nullptr, 0, attnb, PP, 64, PP, 1792, 1);
    attn_pool_kernel<<<NB, 256, 0, stream>>>(attnb, rnn3, feat);
    gemm_kernel<<<dim3(512 / 64, 1), 256, 0, stream>>>(
        feat, 1792, fw, fb, nullptr, 0, out, 512, 64, 512, 1792, 0);
}

// Round 3
// 1711.923 us; speedup vs baseline: 4.1413x; 4.1413x over previous
//
#include <hip/hip_runtime.h>
#include <hip/hip_bf16.h>
#include <math.h>

#define NB 64
#define PP 7

typedef __attribute__((ext_vector_type(8))) short short8;
typedef __attribute__((ext_vector_type(4))) float f32x4;

// round-to-nearest-even bf16 from f32, packed pair -> u32 (lo=a, hi=b)
static __device__ inline unsigned bf16r(float f) {
    unsigned u = __builtin_bit_cast(unsigned, f);
    u += 0x7fffu + ((u >> 16) & 1u);
    return u >> 16;
}
static __device__ inline unsigned pack2(float a, float b) {
    return bf16r(a) | (bf16r(b) << 16);
}

// ---------------------------------------------------------------------------
// crop_avg: x [N,C,H,H] f32 -> out[(n*7+p)*ldo + col0 + c] f32
// ---------------------------------------------------------------------------
__global__ __launch_bounds__(256) void crop_avg_kernel(
    const float* __restrict__ x, const int* __restrict__ patchs,
    float* __restrict__ out, int C, int H, int num, int den,
    int ldo, int col0)
{
    int c = blockIdx.x, n = blockIdx.y;
    extern __shared__ float sm[];
    __shared__ float red[4];
    const float* plane = x + ((size_t)n * C + c) * H * H;
    int tid = threadIdx.x;
    int sz = H * H;
    for (int i = tid; i < sz; i += 256) sm[i] = plane[i];
    __syncthreads();
    int lane = tid & 63, wv = tid >> 6;
    for (int p = 0; p < PP; ++p) {
        int p0 = patchs[(n * PP + p) * 4 + 0];
        int p1 = patchs[(n * PP + p) * 4 + 1];
        int p2 = patchs[(n * PP + p) * 4 + 2];
        int p3 = patchs[(n * PP + p) * 4 + 3];
        int y0 = p0 * num / den, y1 = p1 * num / den;
        int x0 = p2 * num / den, x1 = p3 * num / den;
        float partial = 0.f;
        int xx = x0 + lane;
        if (xx <= x1) {
            for (int y = y0 + wv; y <= y1; y += 4)
                partial += sm[y * H + xx];
        }
        #pragma unroll
        for (int off = 32; off; off >>= 1)
            partial += __shfl_down(partial, off, 64);
        if (lane == 0) red[wv] = partial;
        __syncthreads();
        if (tid == 0) {
            float tot = red[0] + red[1] + red[2] + red[3];
            float area = (float)((y1 - y0 + 1) * (x1 - x0 + 1));
            float v = tot / area;
            if (p0 == 0 && p1 == 0 && p2 == 0 && p3 == 0) v = 0.f;
            out[(size_t)(n * PP + p) * ldo + col0 + c] = v;
        }
        __syncthreads();
    }
}

// ---------------------------------------------------------------------------
// bf16 MFMA gemm, fp32 in/out with on-the-fly bf16 conversion in staging.
// C[m,o] = sum_k X[m,k]*W[o,k].  X:[M,ldx] f32, W:[O,K] f32 row-major.
// Tile: BM=64, BN=256, BK=64. 256 thr = 4 waves; wave w -> cols [64w,64w+64).
// grid = (O/256, M/64, S); split-K chunk = kchunk (mult of 64).
// partial=1: raw acc -> out + z*Mtot*ldo (reduce later). else: +bias, final.
// ---------------------------------------------------------------------------
__global__ __launch_bounds__(256) void gemm_bf16_kernel(
    const float* __restrict__ X, int ldx,
    const float* __restrict__ W, int K,
    const float* __restrict__ bias,
    float* __restrict__ out, int ldo,
    int kchunk, int partial)
{
    __shared__ short Xs[64][72];
    __shared__ short Ws[256][72];
    int tid = threadIdx.x;
    int lane = tid & 63, wv = tid >> 6;
    int m0 = blockIdx.y * 64;
    int o0 = blockIdx.x * 256;
    int z = blockIdx.z;
    int kbeg = z * kchunk, kend = kbeg + kchunk;

    f32x4 acc[4][4];
    #pragma unroll
    for (int i = 0; i < 4; ++i)
        #pragma unroll
        for (int j = 0; j < 4; ++j)
            acc[i][j] = (f32x4){0.f, 0.f, 0.f, 0.f};

    for (int kb = kbeg; kb < kend; kb += 64) {
        #pragma unroll
        for (int i = 0; i < 2; ++i) {
            int cch = tid + 256 * i;
            int r = cch >> 3, col = (cch & 7) * 8;
            const float* src = X + (size_t)(m0 + r) * ldx + kb + col;
            float4 lo = *reinterpret_cast<const float4*>(src);
            float4 hi = *reinterpret_cast<const float4*>(src + 4);
            uint4 v;
            v.x = pack2(lo.x, lo.y); v.y = pack2(lo.z, lo.w);
            v.z = pack2(hi.x, hi.y); v.w = pack2(hi.z, hi.w);
            *reinterpret_cast<uint4*>(&Xs[r][col]) = v;
        }
        #pragma unroll
        for (int i = 0; i < 8; ++i) {
            int cch = tid + 256 * i;
            int r = cch >> 3, col = (cch & 7) * 8;
            const float* src = W + (size_t)(o0 + r) * K + kb + col;
            float4 lo = *reinterpret_cast<const float4*>(src);
            float4 hi = *reinterpret_cast<const float4*>(src + 4);
            uint4 v;
            v.x = pack2(lo.x, lo.y); v.y = pack2(lo.z, lo.w);
            v.z = pack2(hi.x, hi.y); v.w = pack2(hi.z, hi.w);
            *reinterpret_cast<uint4*>(&Ws[r][col]) = v;
        }
        __syncthreads();
        #pragma unroll
        for (int kk = 0; kk < 64; kk += 32) {
            short8 a[4], b[4];
            int ro = lane & 15, kof = kk + (lane >> 4) * 8;
            #pragma unroll
            for (int i = 0; i < 4; ++i)
                a[i] = *reinterpret_cast<const short8*>(&Xs[16 * i + ro][kof]);
            #pragma unroll
            for (int j = 0; j < 4; ++j)
                b[j] = *reinterpret_cast<const short8*>(&Ws[wv * 64 + 16 * j + ro][kof]);
            #pragma unroll
            for (int i = 0; i < 4; ++i)
                #pragma unroll
                for (int j = 0; j < 4; ++j)
                    acc[i][j] = __builtin_amdgcn_mfma_f32_16x16x32_bf16(
                        a[i], b[j], acc[i][j], 0, 0, 0);
        }
        __syncthreads();
    }

    int Mtot = gridDim.y * 64;
    float* dst = out;
    if (partial) dst += (size_t)z * Mtot * ldo;
    int mr = (lane >> 4) * 4;
    #pragma unroll
    for (int j = 0; j < 4; ++j) {
        int o = o0 + wv * 64 + 16 * j + (lane & 15);
        float bv = (!partial && bias) ? bias[o] : 0.f;
        #pragma unroll
        for (int i = 0; i < 4; ++i) {
            #pragma unroll
            for (int r = 0; r < 4; ++r) {
                int m = m0 + 16 * i + mr + r;
                dst[(size_t)m * ldo + o] = acc[i][j][r] + bv;
            }
        }
    }
}

// ---------------------------------------------------------------------------
// reduce split-K partials: out[m*O+o] = act(sum_s partial[s][m][o] + bias[o])
// ---------------------------------------------------------------------------
__global__ __launch_bounds__(256) void reduce_kernel(
    const float* __restrict__ partial, int S, int M, int O,
    const float* __restrict__ bias, int relu, float* __restrict__ out)
{
    int idx = blockIdx.x * 256 + threadIdx.x;
    int tot = M * O;
    if (idx >= tot) return;
    float v = bias[idx % O];
    for (int s = 0; s < S; ++s) v += partial[(size_t)s * tot + idx];
    if (relu) v = fmaxf(v, 0.f);
    out[idx] = v;
}

// ---------------------------------------------------------------------------
// LSTM cell: gates = xgt[n*ldxg + g*H + j] + sum_s partial[s][n][g*H+j]
// torch gate order i,f,g,o. Updates h,c (f32), writes h to dest.
// ---------------------------------------------------------------------------
__global__ __launch_bounds__(256) void lstm_cell_kernel(
    const float* __restrict__ partial, int S,
    const float* __restrict__ xgt, int ldxg,
    float* __restrict__ h, float* __restrict__ c,
    float* __restrict__ dest, int Hd, int ldd)
{
    int idx = blockIdx.x * 256 + threadIdx.x;
    if (idx >= NB * Hd) return;
    int n = idx / Hd, j = idx - n * Hd;
    int H4 = 4 * Hd;
    float g[4];
    #pragma unroll
    for (int gi = 0; gi < 4; ++gi) {
        float v = xgt[(size_t)n * ldxg + gi * Hd + j];
        for (int s = 0; s < S; ++s)
            v += partial[((size_t)s * NB + n) * H4 + gi * Hd + j];
        g[gi] = v;
    }
    float si = 1.f / (1.f + expf(-g[0]));
    float sf = 1.f / (1.f + expf(-g[1]));
    float so = 1.f / (1.f + expf(-g[3]));
    float cn = sf * c[idx] + si * tanhf(g[2]);
    float hn = so * tanhf(cn);
    c[idx] = cn;
    h[idx] = hn;
    dest[(size_t)n * ldd + j] = hn;
}

// ---------------------------------------------------------------------------
// attn logits: attnb[n,p] = relu(h2[n,:] . aw3[p,:] + ab3[p])
// ---------------------------------------------------------------------------
__global__ __launch_bounds__(256) void aw3_kernel(
    const float* __restrict__ h2, const float* __restrict__ aw3,
    const float* __restrict__ ab3, float* __restrict__ attnb)
{
    int n = blockIdx.x;
    int lane = threadIdx.x & 63, wv = threadIdx.x >> 6;
    for (int p = wv; p < PP; p += 4) {
        float s = 0.f;
        for (int k = lane; k < 1792; k += 64)
            s += h2[n * 1792 + k] * aw3[p * 1792 + k];
        #pragma unroll
        for (int off = 32; off; off >>= 1) s += __shfl_down(s, off, 64);
        if (lane == 0) attnb[n * PP + p] = fmaxf(s + ab3[p], 0.f);
    }
}

// ---------------------------------------------------------------------------
// softmax over 7 + weighted pool of rnn3 -> feat [64,1792]
// ---------------------------------------------------------------------------
__global__ __launch_bounds__(256) void attn_pool_kernel(
    const float* __restrict__ attn, const float* __restrict__ rnn3,
    float* __restrict__ feat)
{
    int n = blockIdx.x;
    __shared__ float alpha[PP];
    if (threadIdx.x == 0) {
        float a[PP], mx = -1e30f;
        for (int p = 0; p < PP; ++p) { a[p] = attn[n * PP + p]; mx = fmaxf(mx, a[p]); }
        float s = 0.f;
        for (int p = 0; p < PP; ++p) { a[p] = expf(a[p] - mx); s += a[p]; }
        for (int p = 0; p < PP; ++p) alpha[p] = a[p] / s;
    }
    __syncthreads();
    for (int j = threadIdx.x; j < 1792; j += 256) {
        float s = 0.f;
        #pragma unroll
        for (int p = 0; p < PP; ++p)
            s += rnn3[((size_t)n * PP + p) * 1792 + j] * alpha[p];
        feat[(size_t)n * 1792 + j] = s;
    }
}

// ---------------------------------------------------------------------------

extern "C" void kernel_launch(void* const* d_in, const int* in_sizes, int n_in,
                              void* d_out, int out_size, void* d_ws, size_t ws_size,
                              hipStream_t stream) {
    const float* x1 = (const float*)d_in[0];
    const float* x2 = (const float*)d_in[1];
    const float* x3 = (const float*)d_in[2];
    const int* patchs = (const int*)d_in[3];
    const float* l1_wih = (const float*)d_in[4];
    const float* l1_whh = (const float*)d_in[5];
    const float* l1_b   = (const float*)d_in[6];
    const float* l2_wih = (const float*)d_in[7];
    const float* l2_whh = (const float*)d_in[8];
    const float* l2_b   = (const float*)d_in[9];
    const float* l3_wih = (const float*)d_in[10];
    const float* l3_whh = (const float*)d_in[11];
    const float* l3_b   = (const float*)d_in[12];
    const float* aw1 = (const float*)d_in[13];
    const float* ab1 = (const float*)d_in[14];
    const float* aw2 = (const float*)d_in[15];
    const float* ab2 = (const float*)d_in[16];
    const float* aw3 = (const float*)d_in[17];
    const float* ab3 = (const float*)d_in[18];
    const float* fw  = (const float*)d_in[19];
    const float* fb  = (const float*)d_in[20];
    float* out = (float*)d_out;

    float* ws = (float*)d_ws;
    float* local1 = ws;                       // [448,256]
    float* local2 = local1 + 114688;          // [448,768]
    float* local3 = local2 + 344064;          // [448,1792]
    float* rnn3   = local3;                   // alias: local3 dead after xg3
    float* xg     = local3 + 802816;          // [448,7168] max
    float* partial= xg + 3211264;             // up to 4*64*7168 f32
    float* hbuf   = partial + 1835008;        // [64,1792]
    float* cbuf   = hbuf + 114688;            // [64,1792]
    float* h1     = cbuf + 114688;            // [64,3584]
    float* h2     = h1 + 229376;              // [64,1792]
    float* attnb  = h2 + 114688;              // [64,7]
    float* feat   = attnb + 512;              // [64,1792]

    // ---- crops (f32) ----
    crop_avg_kernel<<<dim3(256, NB), 256, 56 * 56 * 4, stream>>>(
        x1, patchs, local1, 256, 56, 55, 55, 256, 0);
    crop_avg_kernel<<<dim3(512, NB), 256, 28 * 28 * 4, stream>>>(
        x2, patchs, local2, 512, 28, 27, 55, 768, 0);
    crop_avg_kernel<<<dim3(1024, NB), 256, 14 * 14 * 4, stream>>>(
        x3, patchs, local3, 1024, 14, 13, 55, 1792, 0);

    struct LstmCfg {
        const float *Xbuf, *wih, *whh, *b;
        int D, H, recS, reckchunk;
        float* dest_base; int destHT, col0;
    };
    LstmCfg cfgs[3] = {
        { local1, l1_wih, l1_whh, l1_b, 256, 256, 4, 64, local2, 768, 512 },
        { local2, l2_wih, l2_whh, l2_b, 768, 768, 4, 192, local3, 1792, 1024 },
        { local3, l3_wih, l3_whh, l3_b, 1792, 1792, 4, 448, rnn3, 1792, 0 },
    };
    for (int L = 0; L < 3; ++L) {
        LstmCfg& cf = cfgs[L];
        int H4 = 4 * cf.H;
        // xg = X @ wih^T + b : [448, 4H], m = n*7+p
        gemm_bf16_kernel<<<dim3(H4 / 256, 7, 1), 256, 0, stream>>>(
            cf.Xbuf, cf.D, cf.wih, cf.D, cf.b, xg, H4, cf.D, 0);
        (void)hipMemsetAsync(hbuf, 0, (size_t)NB * cf.H * 4, stream);
        (void)hipMemsetAsync(cbuf, 0, (size_t)NB * cf.H * 4, stream);
        for (int t = 0; t < PP; ++t) {
            gemm_bf16_kernel<<<dim3(H4 / 256, 1, cf.recS), 256, 0, stream>>>(
                hbuf, cf.H, cf.whh, cf.H, nullptr, partial, H4, cf.reckchunk, 1);
            float* dest = cf.dest_base + (size_t)t * cf.destHT + cf.col0;
            lstm_cell_kernel<<<(NB * cf.H + 255) / 256, 256, 0, stream>>>(
                partial, cf.recS, xg + (size_t)t * H4, PP * H4,
                hbuf, cbuf, dest, cf.H, PP * cf.destHT);
        }
    }

    // ---- attention MLP ----
    // aw1: [64,12544] x [3584,12544]^T, split-K 7
    gemm_bf16_kernel<<<dim3(14, 1, 7), 256, 0, stream>>>(
        rnn3, 12544, aw1, 12544, nullptr, partial, 3584, 1792, 1);
    reduce_kernel<<<(64 * 3584 + 255) / 256, 256, 0, stream>>>(
        partial, 7, 64, 3584, ab1, 1, h1);
    // aw2: [64,3584] x [1792,3584]^T, split-K 4
    gemm_bf16_kernel<<<dim3(7, 1, 4), 256, 0, stream>>>(
        h1, 3584, aw2, 3584, nullptr, partial, 1792, 896, 1);
    reduce_kernel<<<(64 * 1792 + 255) / 256, 256, 0, stream>>>(
        partial, 4, 64, 1792, ab2, 1, h2);
    aw3_kernel<<<NB, 256, 0, stream>>>(h2, aw3, ab3, attnb);
    attn_pool_kernel<<<NB, 256, 0, stream>>>(attnb, rnn3, feat);
    // fw: [64,1792] x [512,1792]^T, split-K 7
    gemm_bf16_kernel<<<dim3(2, 1, 7), 256, 0, stream>>>(
        feat, 1792, fw, 1792, nullptr, partial, 512, 256, 1);
    reduce_kernel<<<(64 * 512 + 255) / 256, 256, 0, stream>>>(
        partial, 7, 64, 512, fb, 0, out);
}

// Round 4
// 751.730 us; speedup vs baseline: 9.4311x; 2.2773x over previous
//
#include <hip/hip_runtime.h>
#include <hip/hip_bf16.h>
#include <math.h>

#define NB 64
#define PP 7

typedef __attribute__((ext_vector_type(8))) short short8;
typedef __attribute__((ext_vector_type(4))) float f32x4;

// round-to-nearest-even bf16 from f32, packed pair -> u32 (lo=a, hi=b)
static __device__ inline unsigned bf16r(float f) {
    unsigned u = __builtin_bit_cast(unsigned, f);
    u += 0x7fffu + ((u >> 16) & 1u);
    return u >> 16;
}
static __device__ inline unsigned pack2(float a, float b) {
    return bf16r(a) | (bf16r(b) << 16);
}

// ---------------------------------------------------------------------------
// crop v2: one wave-group of H lanes per (n,c) plane. Lane = column; running
// column cumsum over rows; capture cumsum at patch row boundaries; guarded
// shuffle-tree per patch. No LDS, no barriers.
// grid = (C/(4*PPW), N), block 256 = 4 waves, PPW planes per wave.
// ---------------------------------------------------------------------------
template<int H, int PPW>
__global__ __launch_bounds__(256) void crop_kernel(
    const float* __restrict__ x, const int* __restrict__ patchs,
    float* __restrict__ out, int C, int num, int den, int ldo, int col0)
{
    constexpr int ACT = H * PPW;  // active lanes per wave (<=56)
    int tid = threadIdx.x, lane = tid & 63, wv = tid >> 6;
    int n = blockIdx.y;
    int g = lane / H, xl = lane % H;
    bool act = lane < ACT;
    int c = blockIdx.x * (4 * PPW) + wv * PPW + (act ? g : 0);

    int y0m1[PP], y1s[PP], x0s[PP], x1s[PP], zer[PP];
    float rarea[PP];
    #pragma unroll
    for (int p = 0; p < PP; ++p) {
        int p0 = patchs[(n * PP + p) * 4 + 0];
        int p1 = patchs[(n * PP + p) * 4 + 1];
        int p2 = patchs[(n * PP + p) * 4 + 2];
        int p3 = patchs[(n * PP + p) * 4 + 3];
        int y0 = p0 * num / den, y1 = p1 * num / den;
        int xx0 = p2 * num / den, xx1 = p3 * num / den;
        y0m1[p] = y0 - 1; y1s[p] = y1; x0s[p] = xx0; x1s[p] = xx1;
        rarea[p] = 1.f / (float)((y1 - y0 + 1) * (xx1 - xx0 + 1));
        zer[p] = (p0 | p1 | p2 | p3) == 0;
    }

    size_t base = ((size_t)n * C + c) * (H * H) + xl;
    float colcum = 0.f;
    float lo[PP], hi[PP];
    #pragma unroll
    for (int p = 0; p < PP; ++p) { lo[p] = 0.f; hi[p] = 0.f; }

    for (int y = 0; y < H; ++y) {
        float v = x[base + y * H];
        colcum += act ? v : 0.f;
        #pragma unroll
        for (int p = 0; p < PP; ++p) {
            lo[p] = (y == y0m1[p]) ? colcum : lo[p];
            hi[p] = (y == y1s[p]) ? colcum : hi[p];
        }
    }

    #pragma unroll
    for (int p = 0; p < PP; ++p) {
        float d = (act && xl >= x0s[p] && xl <= x1s[p]) ? hi[p] - lo[p] : 0.f;
        #pragma unroll
        for (int off = 32; off >= 1; off >>= 1) {
            if (off < H) {
                float t = __shfl_down(d, off, 64);
                d += (xl + off < H) ? t : 0.f;
            }
        }
        if (act && xl == 0)
            out[(size_t)(n * PP + p) * ldo + col0 + c] = zer[p] ? 0.f : d * rarea[p];
    }
}

// ---------------------------------------------------------------------------
// bf16 MFMA gemm, 64x64 tile. C[m,o] = sum_k X[m,k]*W[o,k].
// X:[M,ldx] f32, W:[O,K] f32 row-major, converted bf16 during staging.
// 256 thr = 4 waves; wave w -> cols [16w,16w+16). grid=(O/64, M/64, S).
// split-K chunk kchunk (mult of 64). partial: raw acc -> out + z*M*ldo.
// ---------------------------------------------------------------------------
__global__ __launch_bounds__(256) void gemm64_kernel(
    const float* __restrict__ X, int ldx,
    const float* __restrict__ W, int K,
    const float* __restrict__ bias,
    float* __restrict__ out, int ldo,
    int kchunk, int partial)
{
    __shared__ short Xs[64][72];
    __shared__ short Ws[64][72];
    int tid = threadIdx.x;
    int lane = tid & 63, wv = tid >> 6;
    int m0 = blockIdx.y * 64;
    int o0 = blockIdx.x * 64;
    int z = blockIdx.z;
    int kbeg = z * kchunk, kend = kbeg + kchunk;

    f32x4 acc[4];
    #pragma unroll
    for (int i = 0; i < 4; ++i) acc[i] = (f32x4){0.f, 0.f, 0.f, 0.f};

    for (int kb = kbeg; kb < kend; kb += 64) {
        #pragma unroll
        for (int i = 0; i < 2; ++i) {
            int cch = tid + 256 * i;
            int r = cch >> 3, col = (cch & 7) * 8;
            const float* src = X + (size_t)(m0 + r) * ldx + kb + col;
            float4 a = *reinterpret_cast<const float4*>(src);
            float4 b = *reinterpret_cast<const float4*>(src + 4);
            uint4 v;
            v.x = pack2(a.x, a.y); v.y = pack2(a.z, a.w);
            v.z = pack2(b.x, b.y); v.w = pack2(b.z, b.w);
            *reinterpret_cast<uint4*>(&Xs[r][col]) = v;
            const float* srcw = W + (size_t)(o0 + r) * K + kb + col;
            float4 c = *reinterpret_cast<const float4*>(srcw);
            float4 d = *reinterpret_cast<const float4*>(srcw + 4);
            uint4 w;
            w.x = pack2(c.x, c.y); w.y = pack2(c.z, c.w);
            w.z = pack2(d.x, d.y); w.w = pack2(d.z, d.w);
            *reinterpret_cast<uint4*>(&Ws[r][col]) = w;
        }
        __syncthreads();
        #pragma unroll
        for (int kk = 0; kk < 64; kk += 32) {
            int ro = lane & 15, kof = kk + (lane >> 4) * 8;
            short8 b = *reinterpret_cast<const short8*>(&Ws[wv * 16 + ro][kof]);
            #pragma unroll
            for (int i = 0; i < 4; ++i) {
                short8 a = *reinterpret_cast<const short8*>(&Xs[16 * i + ro][kof]);
                acc[i] = __builtin_amdgcn_mfma_f32_16x16x32_bf16(a, b, acc[i], 0, 0, 0);
            }
        }
        __syncthreads();
    }

    float* dst = out;
    if (partial) dst += (size_t)z * (gridDim.y * 64) * ldo;
    int o = o0 + wv * 16 + (lane & 15);
    float bv = (!partial && bias) ? bias[o] : 0.f;
    int mr = (lane >> 4) * 4;
    #pragma unroll
    for (int i = 0; i < 4; ++i) {
        #pragma unroll
        for (int r = 0; r < 4; ++r) {
            int m = m0 + 16 * i + mr + r;
            dst[(size_t)m * ldo + o] = acc[i][r] + bv;
        }
    }
}

// ---------------------------------------------------------------------------
// reduce split-K partials: out[m*O+o] = act(sum_s partial[s][m][o] + bias[o])
// ---------------------------------------------------------------------------
__global__ __launch_bounds__(256) void reduce_kernel(
    const float* __restrict__ partial, int S, int M, int O,
    const float* __restrict__ bias, int relu, float* __restrict__ out)
{
    int idx = blockIdx.x * 256 + threadIdx.x;
    int tot = M * O;
    if (idx >= tot) return;
    float v = bias[idx % O];
    for (int s = 0; s < S; ++s) v += partial[(size_t)s * tot + idx];
    if (relu) v = fmaxf(v, 0.f);
    out[idx] = v;
}

// ---------------------------------------------------------------------------
// LSTM cell, float4 per thread. gates = xgt + sum_s partial (unless first).
// torch gate order i,f,g,o. c_prev = 0 if first. Writes h, c, dest.
// ---------------------------------------------------------------------------
__global__ __launch_bounds__(256) void lstm_cell_kernel(
    const float* __restrict__ partial, int S,
    const float* __restrict__ xgt, int ldxg,
    float* __restrict__ h, float* __restrict__ c,
    float* __restrict__ dest, int Hd, int ldd, int first)
{
    int idx = blockIdx.x * 256 + threadIdx.x;
    int q = Hd >> 2;
    if (idx >= NB * q) return;
    int n = idx / q, j4 = (idx - n * q) * 4;
    int H4 = 4 * Hd;

    f32x4 g[4];
    #pragma unroll
    for (int gi = 0; gi < 4; ++gi)
        g[gi] = *reinterpret_cast<const f32x4*>(xgt + (size_t)n * ldxg + gi * Hd + j4);
    if (!first) {
        for (int s = 0; s < S; ++s) {
            const float* pr = partial + ((size_t)s * NB + n) * H4;
            #pragma unroll
            for (int gi = 0; gi < 4; ++gi)
                g[gi] += *reinterpret_cast<const f32x4*>(pr + gi * Hd + j4);
        }
    }
    f32x4 cp = (f32x4){0.f, 0.f, 0.f, 0.f};
    if (!first) cp = *reinterpret_cast<const f32x4*>(c + (size_t)n * Hd + j4);

    f32x4 cn, hn;
    #pragma unroll
    for (int k = 0; k < 4; ++k) {
        float si = 1.f / (1.f + expf(-g[0][k]));
        float sf = 1.f / (1.f + expf(-g[1][k]));
        float so = 1.f / (1.f + expf(-g[3][k]));
        float cc = sf * cp[k] + si * tanhf(g[2][k]);
        cn[k] = cc;
        hn[k] = so * tanhf(cc);
    }
    *reinterpret_cast<f32x4*>(c + (size_t)n * Hd + j4) = cn;
    *reinterpret_cast<f32x4*>(h + (size_t)n * Hd + j4) = hn;
    *reinterpret_cast<f32x4*>(dest + (size_t)n * ldd + j4) = hn;
}

// ---------------------------------------------------------------------------
// attn logits: attnb[n,p] = relu(h2[n,:] . aw3[p,:] + ab3[p])
// ---------------------------------------------------------------------------
__global__ __launch_bounds__(256) void aw3_kernel(
    const float* __restrict__ h2, const float* __restrict__ aw3,
    const float* __restrict__ ab3, float* __restrict__ attnb)
{
    int n = blockIdx.x;
    int lane = threadIdx.x & 63, wv = threadIdx.x >> 6;
    for (int p = wv; p < PP; p += 4) {
        float s = 0.f;
        for (int k = lane; k < 1792; k += 64)
            s += h2[n * 1792 + k] * aw3[p * 1792 + k];
        #pragma unroll
        for (int off = 32; off; off >>= 1) s += __shfl_down(s, off, 64);
        if (lane == 0) attnb[n * PP + p] = fmaxf(s + ab3[p], 0.f);
    }
}

// ---------------------------------------------------------------------------
// softmax over 7 + weighted pool of rnn3 -> feat [64,1792]
// ---------------------------------------------------------------------------
__global__ __launch_bounds__(256) void attn_pool_kernel(
    const float* __restrict__ attn, const float* __restrict__ rnn3,
    float* __restrict__ feat)
{
    int n = blockIdx.x;
    __shared__ float alpha[PP];
    if (threadIdx.x == 0) {
        float a[PP], mx = -1e30f;
        for (int p = 0; p < PP; ++p) { a[p] = attn[n * PP + p]; mx = fmaxf(mx, a[p]); }
        float s = 0.f;
        for (int p = 0; p < PP; ++p) { a[p] = expf(a[p] - mx); s += a[p]; }
        for (int p = 0; p < PP; ++p) alpha[p] = a[p] / s;
    }
    __syncthreads();
    for (int j = threadIdx.x; j < 1792; j += 256) {
        float s = 0.f;
        #pragma unroll
        for (int p = 0; p < PP; ++p)
            s += rnn3[((size_t)n * PP + p) * 1792 + j] * alpha[p];
        feat[(size_t)n * 1792 + j] = s;
    }
}

// ---------------------------------------------------------------------------

extern "C" void kernel_launch(void* const* d_in, const int* in_sizes, int n_in,
                              void* d_out, int out_size, void* d_ws, size_t ws_size,
                              hipStream_t stream) {
    const float* x1 = (const float*)d_in[0];
    const float* x2 = (const float*)d_in[1];
    const float* x3 = (const float*)d_in[2];
    const int* patchs = (const int*)d_in[3];
    const float* l1_wih = (const float*)d_in[4];
    const float* l1_whh = (const float*)d_in[5];
    const float* l1_b   = (const float*)d_in[6];
    const float* l2_wih = (const float*)d_in[7];
    const float* l2_whh = (const float*)d_in[8];
    const float* l2_b   = (const float*)d_in[9];
    const float* l3_wih = (const float*)d_in[10];
    const float* l3_whh = (const float*)d_in[11];
    const float* l3_b   = (const float*)d_in[12];
    const float* aw1 = (const float*)d_in[13];
    const float* ab1 = (const float*)d_in[14];
    const float* aw2 = (const float*)d_in[15];
    const float* ab2 = (const float*)d_in[16];
    const float* aw3 = (const float*)d_in[17];
    const float* ab3 = (const float*)d_in[18];
    const float* fw  = (const float*)d_in[19];
    const float* fb  = (const float*)d_in[20];
    float* out = (float*)d_out;

    float* ws = (float*)d_ws;
    float* local1 = ws;                       // [448,256]
    float* local2 = local1 + 114688;          // [448,768]
    float* local3 = local2 + 344064;          // [448,1792]
    float* rnn3   = local3;                   // alias: local3 dead after xg3
    float* xg     = local3 + 802816;          // [448,7168] max
    float* partial= xg + 3211264;             // 1835008 f32 max
    float* hbuf   = partial + 1835008;        // [64,1792]
    float* cbuf   = hbuf + 114688;            // [64,1792]
    float* h1     = cbuf + 114688;            // [64,3584]
    float* h2     = h1 + 229376;              // [64,1792]
    float* attnb  = h2 + 114688;              // [64,7]
    float* feat   = attnb + 512;              // [64,1792]

    // ---- crops ----
    crop_kernel<56, 1><<<dim3(64, NB), 256, 0, stream>>>(
        x1, patchs, local1, 256, 55, 55, 256, 0);
    crop_kernel<28, 2><<<dim3(64, NB), 256, 0, stream>>>(
        x2, patchs, local2, 512, 27, 55, 768, 0);
    crop_kernel<14, 4><<<dim3(64, NB), 256, 0, stream>>>(
        x3, patchs, local3, 1024, 13, 55, 1792, 0);

    struct LstmCfg {
        const float *Xbuf, *wih, *whh, *b;
        int D, H, recS, reckchunk;
        float* dest_base; int destHT, col0;
    };
    LstmCfg cfgs[3] = {
        { local1, l1_wih, l1_whh, l1_b, 256, 256, 4, 64, local2, 768, 512 },
        { local2, l2_wih, l2_whh, l2_b, 768, 768, 6, 128, local3, 1792, 1024 },
        { local3, l3_wih, l3_whh, l3_b, 1792, 1792, 4, 448, rnn3, 1792, 0 },
    };
    for (int L = 0; L < 3; ++L) {
        LstmCfg& cf = cfgs[L];
        int H4 = 4 * cf.H;
        int cellblk = (NB * cf.H / 4 + 255) / 256;
        // xg = X @ wih^T + b : [448, 4H]
        gemm64_kernel<<<dim3(H4 / 64, 7, 1), 256, 0, stream>>>(
            cf.Xbuf, cf.D, cf.wih, cf.D, cf.b, xg, H4, cf.D, 0);
        for (int t = 0; t < PP; ++t) {
            if (t > 0) {
                gemm64_kernel<<<dim3(H4 / 64, 1, cf.recS), 256, 0, stream>>>(
                    hbuf, cf.H, cf.whh, cf.H, nullptr, partial, H4, cf.reckchunk, 1);
            }
            float* dest = cf.dest_base + (size_t)t * cf.destHT + cf.col0;
            lstm_cell_kernel<<<cellblk, 256, 0, stream>>>(
                partial, cf.recS, xg + (size_t)t * H4, PP * H4,
                hbuf, cbuf, dest, cf.H, PP * cf.destHT, t == 0);
        }
    }

    // ---- attention MLP ----
    // aw1: [64,12544] x [3584,12544]^T, split-K 7
    gemm64_kernel<<<dim3(56, 1, 7), 256, 0, stream>>>(
        rnn3, 12544, aw1, 12544, nullptr, partial, 3584, 1792, 1);
    reduce_kernel<<<(64 * 3584 + 255) / 256, 256, 0, stream>>>(
        partial, 7, 64, 3584, ab1, 1, h1);
    // aw2: [64,3584] x [1792,3584]^T, split-K 4
    gemm64_kernel<<<dim3(28, 1, 4), 256, 0, stream>>>(
        h1, 3584, aw2, 3584, nullptr, partial, 1792, 896, 1);
    reduce_kernel<<<(64 * 1792 + 255) / 256, 256, 0, stream>>>(
        partial, 4, 64, 1792, ab2, 1, h2);
    aw3_kernel<<<NB, 256, 0, stream>>>(h2, aw3, ab3, attnb);
    attn_pool_kernel<<<NB, 256, 0, stream>>>(attnb, rnn3, feat);
    // fw: [64,1792] x [512,1792]^T, split-K 7
    gemm64_kernel<<<dim3(8, 1, 7), 256, 0, stream>>>(
        feat, 1792, fw, 1792, nullptr, partial, 512, 256, 1);
    reduce_kernel<<<(64 * 512 + 255) / 256, 256, 0, stream>>>(
        partial, 7, 64, 512, fb, 0, out);
}

// Round 5
// 641.156 us; speedup vs baseline: 11.0575x; 1.1725x over previous
//
#include <hip/hip_runtime.h>
#include <hip/hip_bf16.h>
#include <math.h>

#define NB 64
#define PP 7

typedef __attribute__((ext_vector_type(8))) short short8;
typedef __attribute__((ext_vector_type(4))) float f32x4;

// round-to-nearest-even bf16 from f32, packed pair -> u32 (lo=a, hi=b)
static __device__ inline unsigned bf16r(float f) {
    unsigned u = __builtin_bit_cast(unsigned, f);
    u += 0x7fffu + ((u >> 16) & 1u);
    return u >> 16;
}
static __device__ inline unsigned pack2(float a, float b) {
    return bf16r(a) | (bf16r(b) << 16);
}

// ---------------------------------------------------------------------------
// crop v3: GRP lanes per (n,c) plane, VEC columns per lane (float4/float2).
// Running column cumsum; capture at patch row boundaries; x-mask + xor-tree
// reduce within GRP-aligned lane group. No LDS, no barriers.
// grid = (C/(4*64/GRP... ), N): planes/block = 4 waves * (64/GRP).
// ---------------------------------------------------------------------------
template<int H, int VEC, int GRP>
__global__ __launch_bounds__(256) void crop_kernel(
    const float* __restrict__ x, const int* __restrict__ patchs,
    float* __restrict__ out, int C, int num, int den, int ldo, int col0)
{
    constexpr int USED = H / VEC;        // active lanes per plane
    constexpr int PPWAVE = 64 / GRP;     // planes per wave
    int tid = threadIdx.x, lane = tid & 63, wv = tid >> 6;
    int n = blockIdx.y;
    int sub = lane / GRP, xl = lane & (GRP - 1);
    bool act = xl < USED;
    int c = blockIdx.x * (4 * PPWAVE) + wv * PPWAVE + sub;

    int y0m1[PP], y1s[PP], x0s[PP], x1s[PP], zer[PP];
    float rarea[PP];
    #pragma unroll
    for (int p = 0; p < PP; ++p) {
        int p0 = patchs[(n * PP + p) * 4 + 0];
        int p1 = patchs[(n * PP + p) * 4 + 1];
        int p2 = patchs[(n * PP + p) * 4 + 2];
        int p3 = patchs[(n * PP + p) * 4 + 3];
        int y0 = p0 * num / den, y1 = p1 * num / den;
        int xx0 = p2 * num / den, xx1 = p3 * num / den;
        y0m1[p] = y0 - 1; y1s[p] = y1; x0s[p] = xx0; x1s[p] = xx1;
        rarea[p] = 1.f / (float)((y1 - y0 + 1) * (xx1 - xx0 + 1));
        zer[p] = (p0 | p1 | p2 | p3) == 0;
    }

    const float* pl = x + ((size_t)n * C + c) * (H * H) + (act ? xl * VEC : 0);

    float cc[VEC];
    float lo[PP][VEC], hi[PP][VEC];
    #pragma unroll
    for (int e = 0; e < VEC; ++e) cc[e] = 0.f;
    #pragma unroll
    for (int p = 0; p < PP; ++p)
        #pragma unroll
        for (int e = 0; e < VEC; ++e) { lo[p][e] = 0.f; hi[p][e] = 0.f; }

    #pragma unroll 4
    for (int y = 0; y < H; ++y) {
        float v[VEC];
        if constexpr (VEC == 4) {
            float4 t = *reinterpret_cast<const float4*>(pl + y * H);
            v[0] = t.x; v[1] = t.y; v[2] = t.z; v[3] = t.w;
        } else {
            float2 t = *reinterpret_cast<const float2*>(pl + y * H);
            v[0] = t.x; v[1] = t.y;
        }
        #pragma unroll
        for (int e = 0; e < VEC; ++e) cc[e] += v[e];
        #pragma unroll
        for (int p = 0; p < PP; ++p) {
            #pragma unroll
            for (int e = 0; e < VEC; ++e) {
                lo[p][e] = (y == y0m1[p]) ? cc[e] : lo[p][e];
                hi[p][e] = (y == y1s[p]) ? cc[e] : hi[p][e];
            }
        }
    }

    #pragma unroll
    for (int p = 0; p < PP; ++p) {
        float d = 0.f;
        #pragma unroll
        for (int e = 0; e < VEC; ++e) {
            int col = xl * VEC + e;
            if (col >= x0s[p] && col <= x1s[p]) d += hi[p][e] - lo[p][e];
        }
        #pragma unroll
        for (int off = GRP / 2; off >= 1; off >>= 1)
            d += __shfl_xor(d, off, 64);
        if (act && xl == 0)
            out[(size_t)(n * PP + p) * ldo + col0 + c] = zer[p] ? 0.f : d * rarea[p];
    }
}

// ---------------------------------------------------------------------------
// bf16 MFMA gemm, 64x64 tile. C[m,o] = sum_k X[m,k]*W[o,k].
// X:[M,ldx] f32, W:[O,K] f32 row-major, converted bf16 during staging.
// 256 thr = 4 waves; wave w -> cols [16w,16w+16). grid=(O/64, M/64, S).
// split-K chunk kchunk (mult of 64). partial: raw acc -> out + z*M*ldo.
// ---------------------------------------------------------------------------
__global__ __launch_bounds__(256) void gemm64_kernel(
    const float* __restrict__ X, int ldx,
    const float* __restrict__ W, int K,
    const float* __restrict__ bias,
    float* __restrict__ out, int ldo,
    int kchunk, int partial)
{
    __shared__ short Xs[64][72];
    __shared__ short Ws[64][72];
    int tid = threadIdx.x;
    int lane = tid & 63, wv = tid >> 6;
    int m0 = blockIdx.y * 64;
    int o0 = blockIdx.x * 64;
    int z = blockIdx.z;
    int kbeg = z * kchunk, kend = kbeg + kchunk;

    f32x4 acc[4];
    #pragma unroll
    for (int i = 0; i < 4; ++i) acc[i] = (f32x4){0.f, 0.f, 0.f, 0.f};

    for (int kb = kbeg; kb < kend; kb += 64) {
        #pragma unroll
        for (int i = 0; i < 2; ++i) {
            int cch = tid + 256 * i;
            int r = cch >> 3, col = (cch & 7) * 8;
            const float* src = X + (size_t)(m0 + r) * ldx + kb + col;
            float4 a = *reinterpret_cast<const float4*>(src);
            float4 b = *reinterpret_cast<const float4*>(src + 4);
            uint4 v;
            v.x = pack2(a.x, a.y); v.y = pack2(a.z, a.w);
            v.z = pack2(b.x, b.y); v.w = pack2(b.z, b.w);
            *reinterpret_cast<uint4*>(&Xs[r][col]) = v;
            const float* srcw = W + (size_t)(o0 + r) * K + kb + col;
            float4 c = *reinterpret_cast<const float4*>(srcw);
            float4 d = *reinterpret_cast<const float4*>(srcw + 4);
            uint4 w;
            w.x = pack2(c.x, c.y); w.y = pack2(c.z, c.w);
            w.z = pack2(d.x, d.y); w.w = pack2(d.z, d.w);
            *reinterpret_cast<uint4*>(&Ws[r][col]) = w;
        }
        __syncthreads();
        #pragma unroll
        for (int kk = 0; kk < 64; kk += 32) {
            int ro = lane & 15, kof = kk + (lane >> 4) * 8;
            short8 b = *reinterpret_cast<const short8*>(&Ws[wv * 16 + ro][kof]);
            #pragma unroll
            for (int i = 0; i < 4; ++i) {
                short8 a = *reinterpret_cast<const short8*>(&Xs[16 * i + ro][kof]);
                acc[i] = __builtin_amdgcn_mfma_f32_16x16x32_bf16(a, b, acc[i], 0, 0, 0);
            }
        }
        __syncthreads();
    }

    float* dst = out;
    if (partial) dst += (size_t)z * (gridDim.y * 64) * ldo;
    int o = o0 + wv * 16 + (lane & 15);
    float bv = (!partial && bias) ? bias[o] : 0.f;
    int mr = (lane >> 4) * 4;
    #pragma unroll
    for (int i = 0; i < 4; ++i) {
        #pragma unroll
        for (int r = 0; r < 4; ++r) {
            int m = m0 + 16 * i + mr + r;
            dst[(size_t)m * ldo + o] = acc[i][r] + bv;
        }
    }
}

// ---------------------------------------------------------------------------
// reduce split-K partials: out[m*O+o] = act(sum_s partial[s][m][o] + bias[o])
// ---------------------------------------------------------------------------
__global__ __launch_bounds__(256) void reduce_kernel(
    const float* __restrict__ partial, int S, int M, int O,
    const float* __restrict__ bias, int relu, float* __restrict__ out)
{
    int idx = blockIdx.x * 256 + threadIdx.x;
    int tot = M * O;
    if (idx >= tot) return;
    float v = bias[idx % O];
    for (int s = 0; s < S; ++s) v += partial[(size_t)s * tot + idx];
    if (relu) v = fmaxf(v, 0.f);
    out[idx] = v;
}

// ---------------------------------------------------------------------------
// LSTM cell, float4 per thread. gates = xgt + sum_s partial (unless first).
// torch gate order i,f,g,o. c_prev = 0 if first. Writes h, c, dest.
// ---------------------------------------------------------------------------
__global__ __launch_bounds__(256) void lstm_cell_kernel(
    const float* __restrict__ partial, int S,
    const float* __restrict__ xgt, int ldxg,
    float* __restrict__ h, float* __restrict__ c,
    float* __restrict__ dest, int Hd, int ldd, int first)
{
    int idx = blockIdx.x * 256 + threadIdx.x;
    int q = Hd >> 2;
    if (idx >= NB * q) return;
    int n = idx / q, j4 = (idx - n * q) * 4;
    int H4 = 4 * Hd;

    f32x4 g[4];
    #pragma unroll
    for (int gi = 0; gi < 4; ++gi)
        g[gi] = *reinterpret_cast<const f32x4*>(xgt + (size_t)n * ldxg + gi * Hd + j4);
    if (!first) {
        for (int s = 0; s < S; ++s) {
            const float* pr = partial + ((size_t)s * NB + n) * H4;
            #pragma unroll
            for (int gi = 0; gi < 4; ++gi)
                g[gi] += *reinterpret_cast<const f32x4*>(pr + gi * Hd + j4);
        }
    }
    f32x4 cp = (f32x4){0.f, 0.f, 0.f, 0.f};
    if (!first) cp = *reinterpret_cast<const f32x4*>(c + (size_t)n * Hd + j4);

    f32x4 cn, hn;
    #pragma unroll
    for (int k = 0; k < 4; ++k) {
        float si = 1.f / (1.f + expf(-g[0][k]));
        float sf = 1.f / (1.f + expf(-g[1][k]));
        float so = 1.f / (1.f + expf(-g[3][k]));
        float cc = sf * cp[k] + si * tanhf(g[2][k]);
        cn[k] = cc;
        hn[k] = so * tanhf(cc);
    }
    *reinterpret_cast<f32x4*>(c + (size_t)n * Hd + j4) = cn;
    *reinterpret_cast<f32x4*>(h + (size_t)n * Hd + j4) = hn;
    *reinterpret_cast<f32x4*>(dest + (size_t)n * ldd + j4) = hn;
}

// ---------------------------------------------------------------------------
// attn logits: attnb[n,p] = relu(h2[n,:] . aw3[p,:] + ab3[p])
// ---------------------------------------------------------------------------
__global__ __launch_bounds__(256) void aw3_kernel(
    const float* __restrict__ h2, const float* __restrict__ aw3,
    const float* __restrict__ ab3, float* __restrict__ attnb)
{
    int n = blockIdx.x;
    int lane = threadIdx.x & 63, wv = threadIdx.x >> 6;
    for (int p = wv; p < PP; p += 4) {
        float s = 0.f;
        for (int k = lane; k < 1792; k += 64)
            s += h2[n * 1792 + k] * aw3[p * 1792 + k];
        #pragma unroll
        for (int off = 32; off; off >>= 1) s += __shfl_down(s, off, 64);
        if (lane == 0) attnb[n * PP + p] = fmaxf(s + ab3[p], 0.f);
    }
}

// ---------------------------------------------------------------------------
// softmax over 7 + weighted pool of rnn3 -> feat [64,1792]
// ---------------------------------------------------------------------------
__global__ __launch_bounds__(256) void attn_pool_kernel(
    const float* __restrict__ attn, const float* __restrict__ rnn3,
    float* __restrict__ feat)
{
    int n = blockIdx.x;
    __shared__ float alpha[PP];
    if (threadIdx.x == 0) {
        float a[PP], mx = -1e30f;
        for (int p = 0; p < PP; ++p) { a[p] = attn[n * PP + p]; mx = fmaxf(mx, a[p]); }
        float s = 0.f;
        for (int p = 0; p < PP; ++p) { a[p] = expf(a[p] - mx); s += a[p]; }
        for (int p = 0; p < PP; ++p) alpha[p] = a[p] / s;
    }
    __syncthreads();
    for (int j = threadIdx.x; j < 1792; j += 256) {
        float s = 0.f;
        #pragma unroll
        for (int p = 0; p < PP; ++p)
            s += rnn3[((size_t)n * PP + p) * 1792 + j] * alpha[p];
        feat[(size_t)n * 1792 + j] = s;
    }
}

// ---------------------------------------------------------------------------

extern "C" void kernel_launch(void* const* d_in, const int* in_sizes, int n_in,
                              void* d_out, int out_size, void* d_ws, size_t ws_size,
                              hipStream_t stream) {
    const float* x1 = (const float*)d_in[0];
    const float* x2 = (const float*)d_in[1];
    const float* x3 = (const float*)d_in[2];
    const int* patchs = (const int*)d_in[3];
    const float* l1_wih = (const float*)d_in[4];
    const float* l1_whh = (const float*)d_in[5];
    const float* l1_b   = (const float*)d_in[6];
    const float* l2_wih = (const float*)d_in[7];
    const float* l2_whh = (const float*)d_in[8];
    const float* l2_b   = (const float*)d_in[9];
    const float* l3_wih = (const float*)d_in[10];
    const float* l3_whh = (const float*)d_in[11];
    const float* l3_b   = (const float*)d_in[12];
    const float* aw1 = (const float*)d_in[13];
    const float* ab1 = (const float*)d_in[14];
    const float* aw2 = (const float*)d_in[15];
    const float* ab2 = (const float*)d_in[16];
    const float* aw3 = (const float*)d_in[17];
    const float* ab3 = (const float*)d_in[18];
    const float* fw  = (const float*)d_in[19];
    const float* fb  = (const float*)d_in[20];
    float* out = (float*)d_out;

    float* ws = (float*)d_ws;
    float* local1 = ws;                       // [448,256]
    float* local2 = local1 + 114688;          // [448,768]
    float* local3 = local2 + 344064;          // [448,1792]
    float* rnn3   = local3;                   // alias: local3 dead after xg3
    float* xg     = local3 + 802816;          // [448,7168] max
    float* partial= xg + 3211264;             // 1835008 f32 max
    float* hbuf   = partial + 1835008;        // [64,1792]
    float* cbuf   = hbuf + 114688;            // [64,1792]
    float* h1     = cbuf + 114688;            // [64,3584]
    float* h2     = h1 + 229376;              // [64,1792]
    float* attnb  = h2 + 114688;              // [64,7]
    float* feat   = attnb + 512;              // [64,1792]

    // ---- crops ----
    crop_kernel<56, 4, 16><<<dim3(16, NB), 256, 0, stream>>>(
        x1, patchs, local1, 256, 55, 55, 256, 0);
    crop_kernel<28, 4, 8><<<dim3(16, NB), 256, 0, stream>>>(
        x2, patchs, local2, 512, 27, 55, 768, 0);
    crop_kernel<14, 2, 8><<<dim3(32, NB), 256, 0, stream>>>(
        x3, patchs, local3, 1024, 13, 55, 1792, 0);

    struct LstmCfg {
        const float *Xbuf, *wih, *whh, *b;
        int D, H, recS, reckchunk;
        float* dest_base; int destHT, col0;
    };
    LstmCfg cfgs[3] = {
        { local1, l1_wih, l1_whh, l1_b, 256, 256, 4, 64, local2, 768, 512 },
        { local2, l2_wih, l2_whh, l2_b, 768, 768, 6, 128, local3, 1792, 1024 },
        { local3, l3_wih, l3_whh, l3_b, 1792, 1792, 4, 448, rnn3, 1792, 0 },
    };
    for (int L = 0; L < 3; ++L) {
        LstmCfg& cf = cfgs[L];
        int H4 = 4 * cf.H;
        int cellblk = (NB * cf.H / 4 + 255) / 256;
        // xg = X @ wih^T + b : [448, 4H]
        gemm64_kernel<<<dim3(H4 / 64, 7, 1), 256, 0, stream>>>(
            cf.Xbuf, cf.D, cf.wih, cf.D, cf.b, xg, H4, cf.D, 0);
        for (int t = 0; t < PP; ++t) {
            if (t > 0) {
                gemm64_kernel<<<dim3(H4 / 64, 1, cf.recS), 256, 0, stream>>>(
                    hbuf, cf.H, cf.whh, cf.H, nullptr, partial, H4, cf.reckchunk, 1);
            }
            float* dest = cf.dest_base + (size_t)t * cf.destHT + cf.col0;
            lstm_cell_kernel<<<cellblk, 256, 0, stream>>>(
                partial, cf.recS, xg + (size_t)t * H4, PP * H4,
                hbuf, cbuf, dest, cf.H, PP * cf.destHT, t == 0);
        }
    }

    // ---- attention MLP ----
    // aw1: [64,12544] x [3584,12544]^T, split-K 7
    gemm64_kernel<<<dim3(56, 1, 7), 256, 0, stream>>>(
        rnn3, 12544, aw1, 12544, nullptr, partial, 3584, 1792, 1);
    reduce_kernel<<<(64 * 3584 + 255) / 256, 256, 0, stream>>>(
        partial, 7, 64, 3584, ab1, 1, h1);
    // aw2: [64,3584] x [1792,3584]^T, split-K 4
    gemm64_kernel<<<dim3(28, 1, 4), 256, 0, stream>>>(
        h1, 3584, aw2, 3584, nullptr, partial, 1792, 896, 1);
    reduce_kernel<<<(64 * 1792 + 255) / 256, 256, 0, stream>>>(
        partial, 4, 64, 1792, ab2, 1, h2);
    aw3_kernel<<<NB, 256, 0, stream>>>(h2, aw3, ab3, attnb);
    attn_pool_kernel<<<NB, 256, 0, stream>>>(attnb, rnn3, feat);
    // fw: [64,1792] x [512,1792]^T, split-K 7
    gemm64_kernel<<<dim3(8, 1, 7), 256, 0, stream>>>(
        feat, 1792, fw, 1792, nullptr, partial, 512, 256, 1);
    reduce_kernel<<<(64 * 512 + 255) / 256, 256, 0, stream>>>(
        partial, 7, 64, 512, fb, 0, out);
}